// Round 4
// baseline (560.465 us; speedup 1.0000x reference)
//
#include <hip/hip_runtime.h>
#include <hip/hip_bf16.h>
#include <math.h>

#define B_DIM 4096
#define D_IN  2048
#define D_HID 3584
#define D_OUT 2048

typedef __bf16 bf16;
typedef float  floatx4 __attribute__((ext_vector_type(4)));
typedef bf16   bf16x8  __attribute__((ext_vector_type(8)));
typedef bf16   bf16x4  __attribute__((ext_vector_type(4)));

typedef __attribute__((address_space(1))) const void* gptr1;
typedef __attribute__((address_space(3))) void*       lptr3;

__device__ __forceinline__ void load_lds16(const void* g, void* l) {
    __builtin_amdgcn_global_load_lds((gptr1)g, (lptr3)l, 16, 0, 0);
}

struct HL { bf16 h, l; };
__device__ __forceinline__ HL split2(float v) {
    HL r;
    r.h = (bf16)v;
    r.l = (bf16)(v - (float)r.h);
    return r;
}

// ---------------------------------------------------------------------------
// Vesica (fp32 in): x_overlap = x * (1 + relu(1 - |dist - 1|)); emit bf16 hi/lo
// ---------------------------------------------------------------------------
__global__ __launch_bounds__(256) void vesica_kernel(const float* __restrict__ x,
                                                     bf16* __restrict__ xh,
                                                     bf16* __restrict__ xl) {
    const int b  = blockIdx.x;
    const int bp = (b == 0) ? (B_DIM - 1) : (b - 1);
    const int t  = threadIdx.x;

    const floatx4* xr = (const floatx4*)(x + (size_t)b  * D_IN);
    const floatx4* pr = (const floatx4*)(x + (size_t)bp * D_IN);
    const floatx4 v0 = xr[t * 2], v1 = xr[t * 2 + 1];
    const floatx4 p0 = pr[t * 2], p1 = pr[t * 2 + 1];

    float s = 0.f;
#pragma unroll
    for (int j = 0; j < 4; ++j) {
        const float d0 = v0[j] - p0[j], d1 = v1[j] - p1[j];
        s += d0 * d0 + d1 * d1;
    }
#pragma unroll
    for (int off = 32; off > 0; off >>= 1) s += __shfl_down(s, off, 64);

    __shared__ float red[4];
    const int wave = t >> 6, lane = t & 63;
    if (lane == 0) red[wave] = s;
    __syncthreads();
    const float dist = sqrtf(red[0] + red[1] + red[2] + red[3]);
    const float sc   = 1.f + fmaxf(0.f, 1.f - fabsf(dist - 1.f));

    bf16x8 h, l;
#pragma unroll
    for (int j = 0; j < 4; ++j) {
        const HL a  = split2(v0[j] * sc);
        const HL b2 = split2(v1[j] * sc);
        h[j] = a.h;      l[j] = a.l;
        h[4 + j] = b2.h; l[4 + j] = b2.l;
    }
    ((bf16x8*)(xh + (size_t)b * D_IN))[t] = h;
    ((bf16x8*)(xl + (size_t)b * D_IN))[t] = l;
}

// ---------------------------------------------------------------------------
// Split fp32 weight array into bf16 hi/lo.
// ---------------------------------------------------------------------------
__global__ __launch_bounds__(256) void split_kernel(const float* __restrict__ w,
                                                    bf16* __restrict__ wh,
                                                    bf16* __restrict__ wl) {
    const size_t i = (size_t)blockIdx.x * 256 + threadIdx.x;
    const floatx4 a = ((const floatx4*)w)[i * 2];
    const floatx4 b = ((const floatx4*)w)[i * 2 + 1];
    bf16x8 h, l;
#pragma unroll
    for (int j = 0; j < 4; ++j) {
        const HL u = split2(a[j]);
        const HL v = split2(b[j]);
        h[j] = u.h;     l[j] = u.l;
        h[4 + j] = v.h; l[4 + j] = v.l;
    }
    ((bf16x8*)wh)[i] = h;
    ((bf16x8*)wl)[i] = l;
}

// ---------------------------------------------------------------------------
// Flip W_female [2048,3584] along axis 1, split into bf16 hi/lo.
// ---------------------------------------------------------------------------
__global__ __launch_bounds__(256) void flipsplit_kernel(const float* __restrict__ w,
                                                        bf16* __restrict__ wh,
                                                        bf16* __restrict__ wl) {
    const int i = blockIdx.x * 256 + threadIdx.x;
    const int o = i / 448;
    const int g = i - o * 448;
    const float* src = w + (size_t)o * 3584 + (size_t)(447 - g) * 8;
    const floatx4 a = ((const floatx4*)src)[0];
    const floatx4 b = ((const floatx4*)src)[1];
    bf16x8 h, l;
#pragma unroll
    for (int j = 0; j < 4; ++j) {
        const HL u = split2(b[3 - j]);   // out[0..3] = src[7..4]
        const HL v = split2(a[3 - j]);   // out[4..7] = src[3..0]
        h[j] = u.h;     l[j] = u.l;
        h[4 + j] = v.h; l[4 + j] = v.l;
    }
    ((bf16x8*)wh)[(size_t)o * 448 + g] = h;
    ((bf16x8*)wl)[(size_t)o * 448 + g] = l;
}

// ---------------------------------------------------------------------------
// Transpose + phase-scale + split: WflT[d,h] = P(h) * Wfl[h,d], bf16 hi/lo.
// P(h) = cos/sin(2pi*(h>>9)/7) for h%512 in {0,1}, else 1. 64x64 LDS tile.
// ---------------------------------------------------------------------------
__global__ __launch_bounds__(256) void tsplit_kernel(const float* __restrict__ w,
                                                     bf16* __restrict__ th,
                                                     bf16* __restrict__ tl) {
    __shared__ float tile[64][65];
    const int d0 = blockIdx.x * 64;   // 32 tiles along d
    const int h0 = blockIdx.y * 64;   // 56 tiles along h
    const int t  = threadIdx.x;
    const int r  = t >> 4;            // 0..15
    const int cg = (t & 15) << 2;     // 0..60

#pragma unroll
    for (int i = 0; i < 4; ++i) {
        const int hr = r + i * 16;
        const floatx4 v = *(const floatx4*)&w[(size_t)(h0 + hr) * 2048 + d0 + cg];
        tile[hr][cg]     = v[0];
        tile[hr][cg + 1] = v[1];
        tile[hr][cg + 2] = v[2];
        tile[hr][cg + 3] = v[3];
    }
    __syncthreads();

    float pm[4];
#pragma unroll
    for (int j = 0; j < 4; ++j) {
        const int h  = h0 + cg + j;
        const int hm = h & 511;
        float p = 1.f;
        if (hm < 2) {
            const float ph = 0.8975979010256552f * (float)(h >> 9); // 2pi/7*c
            p = (hm == 0) ? cosf(ph) : sinf(ph);
        }
        pm[j] = p;
    }

#pragma unroll
    for (int i = 0; i < 4; ++i) {
        const int dr = r + i * 16;
        bf16x4 hh, ll;
#pragma unroll
        for (int j = 0; j < 4; ++j) {
            const HL u = split2(tile[cg + j][dr] * pm[j]);
            hh[j] = u.h;
            ll[j] = u.l;
        }
        const size_t o = (size_t)(d0 + dr) * 3584 + h0 + cg;
        *(bf16x4*)&th[o] = hh;
        *(bf16x4*)&tl[o] = ll;
    }
}

// ---------------------------------------------------------------------------
// Uniform bf16x3 GEMM, C = A @ B^T. 128x128 tile, BK=32, 256 threads
// (4 waves = 2M x 2N, wave tile 64x64). Double-buffered LDS (64 KB ->
// 2 blocks/CU). T4 counted-vmcnt pipeline (m218/AITER pattern):
//   stage(t+1)                      // 8 global_load_lds per thread
//   s_waitcnt vmcnt(8)              // tile t's 8 loads done; t+1's fly on
//   s_barrier                       // all waves' t-loads landed (per-wave
//                                   //   vmcnt + barrier = workgroup-wide)
//   frag reads + MFMAs (tile t)     // compiler inserts lgkmcnt before use
//   s_barrier                       // all t-reads done before t+2 overwrite
// vmcnt never drains to 0 in the main loop; last tile peeled with vmcnt(0).
// T2 swizzle (verified 0 conflicts): LDS slot q linear, global src chunk
// p = q ^ ((q>>3)&7) (involution); reads XOR the same mask (rule #21).
// BF16OUT=1: write bf16 hi/lo (C0,C1). BF16OUT=0: write f32 (C0).
// ---------------------------------------------------------------------------
template<int BF16OUT>
__global__ __launch_bounds__(256, 2) void gemm3_db(const bf16* __restrict__ Ah,
                                                   const bf16* __restrict__ Al,
                                                   const bf16* __restrict__ Bh,
                                                   const bf16* __restrict__ Bl,
                                                   void* __restrict__ C0p,
                                                   void* __restrict__ C1p,
                                                   int M, int N, int K) {
    __shared__ bf16 sAh[2][4096], sAl[2][4096];   // 128 rows x 32 k per buf
    __shared__ bf16 sBh[2][4096], sBl[2][4096];

    const int tid  = threadIdx.x;
    const int wave = tid >> 6;
    const int lane = tid & 63;
    const int m0   = blockIdx.y * 128;
    const int n0   = blockIdx.x * 128;
    const int wm   = wave & 1;
    const int wn   = wave >> 1;

    floatx4 acc[4][4];
#pragma unroll
    for (int i = 0; i < 4; ++i)
#pragma unroll
        for (int j = 0; j < 4; ++j) acc[i][j] = (floatx4){0.f, 0.f, 0.f, 0.f};

    const int lr  = lane & 15;
    const int cq  = lane >> 4;        // logical chunk 0..3 (k = cq*8)
    const int hsw = (lr >> 1) & 7;    // == ((row<<2)>>3)&7 for fragment rows

    auto stage = [&](int kt, int bsel) {
#pragma unroll
        for (int i = 0; i < 2; ++i) {
            const int q = (i << 8) + tid;            // 0..511 (LDS chunk slot)
            const int p = q ^ ((q >> 3) & 7);        // swizzled src chunk-id
            const int r = p >> 2, c = p & 3;
            const size_t ga = (size_t)(m0 + r) * K + kt + c * 8;
            const size_t gb = (size_t)(n0 + r) * K + kt + c * 8;
            load_lds16(&Ah[ga], &sAh[bsel][q << 3]);
            load_lds16(&Al[ga], &sAl[bsel][q << 3]);
            load_lds16(&Bh[gb], &sBh[bsel][q << 3]);
            load_lds16(&Bl[gb], &sBl[bsel][q << 3]);
        }
    };

    auto compute = [&](int bsel) {
        bf16x8 ahf[4], alf[4];
#pragma unroll
        for (int mi = 0; mi < 4; ++mi) {
            const int row = wm * 64 + mi * 16 + lr;
            const int off = (((row << 2) + cq) ^ hsw) << 3;
            ahf[mi] = *(const bf16x8*)&sAh[bsel][off];
            alf[mi] = *(const bf16x8*)&sAl[bsel][off];
        }
#pragma unroll
        for (int ni = 0; ni < 4; ++ni) {
            const int row = wn * 64 + ni * 16 + lr;
            const int off = (((row << 2) + cq) ^ hsw) << 3;
            const bf16x8 bh = *(const bf16x8*)&sBh[bsel][off];
            const bf16x8 bl = *(const bf16x8*)&sBl[bsel][off];
#pragma unroll
            for (int mi = 0; mi < 4; ++mi) {
                acc[mi][ni] = __builtin_amdgcn_mfma_f32_16x16x32_bf16(
                    ahf[mi], bh, acc[mi][ni], 0, 0, 0);
                acc[mi][ni] = __builtin_amdgcn_mfma_f32_16x16x32_bf16(
                    alf[mi], bh, acc[mi][ni], 0, 0, 0);
                acc[mi][ni] = __builtin_amdgcn_mfma_f32_16x16x32_bf16(
                    ahf[mi], bl, acc[mi][ni], 0, 0, 0);
            }
        }
    };

    stage(0, 0);                       // 8 loads in flight

    int buf = 0;
    for (int kt = 0; kt < K - 32; kt += 32) {
        stage(kt + 32, buf ^ 1);       // +8 -> 16 in flight

        // wait for tile t's 8 loads only; t+1's stay in flight across compute
        asm volatile("s_waitcnt vmcnt(8)" ::: "memory");
        __builtin_amdgcn_s_barrier();

        compute(buf);

        asm volatile("" ::: "memory"); // keep LDS reads above the barrier
        __builtin_amdgcn_s_barrier();  // t-reads done before t+2 overwrites
        buf ^= 1;
    }

    // peeled last tile: nothing left in flight behind it -> full drain
    asm volatile("s_waitcnt vmcnt(0)" ::: "memory");
    __builtin_amdgcn_s_barrier();
    compute(buf);

    const int rq = (lane >> 4) << 2;
    const int cl = lane & 15;
#pragma unroll
    for (int mi = 0; mi < 4; ++mi) {
#pragma unroll
        for (int ni = 0; ni < 4; ++ni) {
            const int col = n0 + wn * 64 + ni * 16 + cl;
#pragma unroll
            for (int r = 0; r < 4; ++r) {
                const int row = m0 + wm * 64 + mi * 16 + rq + r;
                const size_t idx = (size_t)row * N + col;
                if constexpr (BF16OUT) {
                    const HL u = split2(acc[mi][ni][r]);
                    ((bf16*)C0p)[idx] = u.h;
                    ((bf16*)C1p)[idx] = u.l;
                } else {
                    ((float*)C0p)[idx] = acc[mi][ni][r];
                }
            }
        }
    }
}

// ---------------------------------------------------------------------------
// Combine: phase_lock = sigmoid(male . female); out = pl*male + (1-pl)*female
// ---------------------------------------------------------------------------
__global__ __launch_bounds__(256) void combine_kernel(const float* __restrict__ male,
                                                      const float* __restrict__ female,
                                                      float* __restrict__ out) {
    const int b = blockIdx.x;
    const int t = threadIdx.x;

    const floatx4* m4 = (const floatx4*)(male   + (size_t)b * D_OUT);
    const floatx4* f4 = (const floatx4*)(female + (size_t)b * D_OUT);
    const floatx4 mv0 = m4[t * 2], mv1 = m4[t * 2 + 1];
    const floatx4 fv0 = f4[t * 2], fv1 = f4[t * 2 + 1];

    float s = 0.f;
#pragma unroll
    for (int j = 0; j < 4; ++j) s += mv0[j] * fv0[j] + mv1[j] * fv1[j];
#pragma unroll
    for (int off = 32; off > 0; off >>= 1) s += __shfl_down(s, off, 64);

    __shared__ float red[4];
    const int wave = t >> 6, lane = t & 63;
    if (lane == 0) red[wave] = s;
    __syncthreads();
    const float dot = red[0] + red[1] + red[2] + red[3];
    const float pl  = 1.f / (1.f + expf(-dot));

    floatx4 o0, o1;
#pragma unroll
    for (int j = 0; j < 4; ++j) {
        o0[j] = pl * mv0[j] + (1.f - pl) * fv0[j];
        o1[j] = pl * mv1[j] + (1.f - pl) * fv1[j];
    }
    floatx4* o4 = (floatx4*)(out + (size_t)b * D_OUT);
    o4[t * 2]     = o0;
    o4[t * 2 + 1] = o1;
}

// ---------------------------------------------------------------------------
// Pipeline:  male = xo @ (Wm P Wfl)^T,  female = xo @ (Wfe_flip P Wfl)^T
// ---------------------------------------------------------------------------
extern "C" void kernel_launch(void* const* d_in, const int* in_sizes, int n_in,
                              void* d_out, int out_size, void* d_ws, size_t ws_size,
                              hipStream_t stream) {
    const float* x   = (const float*)d_in[0];
    const float* Wfl = (const float*)d_in[1]; // [7,512,2048] == [3584,2048]
    const float* Wm  = (const float*)d_in[2]; // [2048,3584]
    const float* Wfe = (const float*)d_in[3]; // [2048,3584]
    float* out = (float*)d_out;
    (void)in_sizes; (void)n_in; (void)out_size; (void)ws_size;

    char* ws = (char*)d_ws;
    bf16*  xo_hi   = (bf16*)(ws);                    // 4096x2048 = 16,777,216
    bf16*  xo_lo   = (bf16*)(ws + 16777216);         // 16,777,216
    bf16*  Wc_hi   = (bf16*)(ws + 33554432);         // 4096x2048 = 16,777,216
    bf16*  Wc_lo   = (bf16*)(ws + 50331648);         // 16,777,216 -> 67,108,864
    // overlay phase A (dead after weight-combine GEMM):
    bf16*  WflT_hi = (bf16*)(ws + 67108864);         // 2048x3584 = 14,680,064
    bf16*  WflT_lo = (bf16*)(ws + 81788928);         // -> 96,468,992
    bf16*  Wcat_hi = (bf16*)(ws + 96468992);         // 4096x3584 = 29,360,128
    bf16*  Wcat_lo = (bf16*)(ws + 125829120);        // -> 155,189,248
    // overlay phase B (after weight-combine GEMM):
    float* male    = (float*)(ws + 67108864);        // 4096x2048 f32 = 33,554,432
    float* female  = (float*)(ws + 100663296);       // -> 134,217,728

    // 1. vesica scaling (fp32 -> bf16 hi/lo)
    vesica_kernel<<<B_DIM, 256, 0, stream>>>(x, xo_hi, xo_lo);

    // 2. transpose + phase-scale + split Wfl -> WflT [2048, 3584]
    tsplit_kernel<<<dim3(D_IN / 64, D_HID / 64), 256, 0, stream>>>(Wfl, WflT_hi, WflT_lo);

    // 3. Wcat = [Wm ; Wfe_flip], bf16 hi/lo [4096, 3584]
    split_kernel<<<(D_OUT * D_HID / 8) / 256, 256, 0, stream>>>(Wm, Wcat_hi, Wcat_lo);
    flipsplit_kernel<<<(D_OUT * (D_HID / 8)) / 256, 256, 0, stream>>>(
        Wfe, Wcat_hi + (size_t)D_OUT * D_HID, Wcat_lo + (size_t)D_OUT * D_HID);

    // 4. weight combine: Wc[4096,2048] = Wcat @ WflT^T  (K=3584, bf16 hi/lo out)
    //    grid 16x32 = 512 blocks, 2/CU, 64 KB LDS dbuf
    gemm3_db<1><<<dim3(D_IN / 128, (2 * D_OUT) / 128), 256, 0, stream>>>(
        Wcat_hi, Wcat_lo, WflT_hi, WflT_lo, Wc_hi, Wc_lo,
        2 * D_OUT, D_IN, D_HID);

    // 5a. male = xo @ Wc_male^T  (K=2048, fp32 out)
    gemm3_db<0><<<dim3(D_OUT / 128, B_DIM / 128), 256, 0, stream>>>(
        xo_hi, xo_lo, Wc_hi, Wc_lo, male, nullptr,
        B_DIM, D_OUT, D_IN);

    // 5b. female = xo @ Wc_female^T  (K=2048, fp32 out)
    gemm3_db<0><<<dim3(D_OUT / 128, B_DIM / 128), 256, 0, stream>>>(
        xo_hi, xo_lo,
        Wc_hi + (size_t)D_OUT * D_IN, Wc_lo + (size_t)D_OUT * D_IN,
        female, nullptr, B_DIM, D_OUT, D_IN);

    // 6. sigmoid phase-lock blend (fp32 out)
    combine_kernel<<<B_DIM, 256, 0, stream>>>(male, female, out);
}

// Round 5
// 476.824 us; speedup vs baseline: 1.1754x; 1.1754x over previous
//
#include <hip/hip_runtime.h>
#include <hip/hip_bf16.h>
#include <math.h>

#define B_DIM 4096
#define D_IN  2048
#define D_HID 3584
#define D_OUT 2048

typedef __bf16 bf16;
typedef float  floatx4 __attribute__((ext_vector_type(4)));
typedef bf16   bf16x8  __attribute__((ext_vector_type(8)));
typedef bf16   bf16x4  __attribute__((ext_vector_type(4)));

typedef __attribute__((address_space(1))) const void* gptr1;
typedef __attribute__((address_space(3))) void*       lptr3;

__device__ __forceinline__ void load_lds16(const void* g, void* l) {
    __builtin_amdgcn_global_load_lds((gptr1)g, (lptr3)l, 16, 0, 0);
}

struct HL { bf16 h, l; };
__device__ __forceinline__ HL split2(float v) {
    HL r;
    r.h = (bf16)v;
    r.l = (bf16)(v - (float)r.h);
    return r;
}

// T1 XCD-aware tile remap (bijective for nwg = 512 = 16x32, nwg%8==0).
// Dispatch id d -> XCD = d&7 (HW round-robin); each XCD owns 2 adjacent
// B-panel columns (~4MB = its L2) and walks M, A-panel reused on
// consecutive blocks: nx = 2*xcd + (r&1), my = r>>1.
__device__ __forceinline__ void xcd_tile(int& n0, int& m0) {
    const int d  = (int)(blockIdx.x + gridDim.x * blockIdx.y);
    const int r  = d >> 3;
    const int nx = ((d & 7) << 1) | (r & 1);
    const int my = r >> 1;
    n0 = nx * 128;
    m0 = my * 128;
}

// ---------------------------------------------------------------------------
// Vesica (fp32 in): x_overlap = x * (1 + relu(1 - |dist - 1|)); emit bf16 hi/lo
// ---------------------------------------------------------------------------
__global__ __launch_bounds__(256) void vesica_kernel(const float* __restrict__ x,
                                                     bf16* __restrict__ xh,
                                                     bf16* __restrict__ xl) {
    const int b  = blockIdx.x;
    const int bp = (b == 0) ? (B_DIM - 1) : (b - 1);
    const int t  = threadIdx.x;

    const floatx4* xr = (const floatx4*)(x + (size_t)b  * D_IN);
    const floatx4* pr = (const floatx4*)(x + (size_t)bp * D_IN);
    const floatx4 v0 = xr[t * 2], v1 = xr[t * 2 + 1];
    const floatx4 p0 = pr[t * 2], p1 = pr[t * 2 + 1];

    float s = 0.f;
#pragma unroll
    for (int j = 0; j < 4; ++j) {
        const float d0 = v0[j] - p0[j], d1 = v1[j] - p1[j];
        s += d0 * d0 + d1 * d1;
    }
#pragma unroll
    for (int off = 32; off > 0; off >>= 1) s += __shfl_down(s, off, 64);

    __shared__ float red[4];
    const int wave = t >> 6, lane = t & 63;
    if (lane == 0) red[wave] = s;
    __syncthreads();
    const float dist = sqrtf(red[0] + red[1] + red[2] + red[3]);
    const float sc   = 1.f + fmaxf(0.f, 1.f - fabsf(dist - 1.f));

    bf16x8 h, l;
#pragma unroll
    for (int j = 0; j < 4; ++j) {
        const HL a  = split2(v0[j] * sc);
        const HL b2 = split2(v1[j] * sc);
        h[j] = a.h;      l[j] = a.l;
        h[4 + j] = b2.h; l[4 + j] = b2.l;
    }
    ((bf16x8*)(xh + (size_t)b * D_IN))[t] = h;
    ((bf16x8*)(xl + (size_t)b * D_IN))[t] = l;
}

// ---------------------------------------------------------------------------
// Fused Wcat build: rows 0..2047 = split(Wm), rows 2048..4095 = split(flip(Wfe)).
// One launch instead of two; branch is block-uniform (448*2048 % 256 == 0).
// ---------------------------------------------------------------------------
__global__ __launch_bounds__(256) void wcat_kernel(const float* __restrict__ Wm,
                                                   const float* __restrict__ Wfe,
                                                   bf16* __restrict__ wh,
                                                   bf16* __restrict__ wl) {
    const int i = blockIdx.x * 256 + threadIdx.x;   // 0 .. 4096*448-1
    const int o = i / 448;                          // output row
    const int g = i - o * 448;                      // 8-elem group
    bf16x8 h, l;
    if (o < 2048) {
        const float* src = Wm + (size_t)o * 3584 + (size_t)g * 8;
        const floatx4 a = ((const floatx4*)src)[0];
        const floatx4 b = ((const floatx4*)src)[1];
#pragma unroll
        for (int j = 0; j < 4; ++j) {
            const HL u = split2(a[j]);
            const HL v = split2(b[j]);
            h[j] = u.h;     l[j] = u.l;
            h[4 + j] = v.h; l[4 + j] = v.l;
        }
    } else {
        const float* src = Wfe + (size_t)(o - 2048) * 3584 + (size_t)(447 - g) * 8;
        const floatx4 a = ((const floatx4*)src)[0];
        const floatx4 b = ((const floatx4*)src)[1];
#pragma unroll
        for (int j = 0; j < 4; ++j) {
            const HL u = split2(b[3 - j]);   // out[0..3] = src[7..4]
            const HL v = split2(a[3 - j]);   // out[4..7] = src[3..0]
            h[j] = u.h;     l[j] = u.l;
            h[4 + j] = v.h; l[4 + j] = v.l;
        }
    }
    ((bf16x8*)wh)[i] = h;
    ((bf16x8*)wl)[i] = l;
}

// ---------------------------------------------------------------------------
// Transpose + phase-scale + split: WflT[d,h] = P(h) * Wfl[h,d], bf16 hi/lo.
// P(h) = cos/sin(2pi*(h>>9)/7) for h%512 in {0,1}, else 1. 64x64 LDS tile.
// ---------------------------------------------------------------------------
__global__ __launch_bounds__(256) void tsplit_kernel(const float* __restrict__ w,
                                                     bf16* __restrict__ th,
                                                     bf16* __restrict__ tl) {
    __shared__ float tile[64][65];
    const int d0 = blockIdx.x * 64;   // 32 tiles along d
    const int h0 = blockIdx.y * 64;   // 56 tiles along h
    const int t  = threadIdx.x;
    const int r  = t >> 4;            // 0..15
    const int cg = (t & 15) << 2;     // 0..60

#pragma unroll
    for (int i = 0; i < 4; ++i) {
        const int hr = r + i * 16;
        const floatx4 v = *(const floatx4*)&w[(size_t)(h0 + hr) * 2048 + d0 + cg];
        tile[hr][cg]     = v[0];
        tile[hr][cg + 1] = v[1];
        tile[hr][cg + 2] = v[2];
        tile[hr][cg + 3] = v[3];
    }
    __syncthreads();

    float pm[4];
#pragma unroll
    for (int j = 0; j < 4; ++j) {
        const int h  = h0 + cg + j;
        const int hm = h & 511;
        float p = 1.f;
        if (hm < 2) {
            const float ph = 0.8975979010256552f * (float)(h >> 9); // 2pi/7*c
            p = (hm == 0) ? cosf(ph) : sinf(ph);
        }
        pm[j] = p;
    }

#pragma unroll
    for (int i = 0; i < 4; ++i) {
        const int dr = r + i * 16;
        bf16x4 hh, ll;
#pragma unroll
        for (int j = 0; j < 4; ++j) {
            const HL u = split2(tile[cg + j][dr] * pm[j]);
            hh[j] = u.h;
            ll[j] = u.l;
        }
        const size_t o = (size_t)(d0 + dr) * 3584 + h0 + cg;
        *(bf16x4*)&th[o] = hh;
        *(bf16x4*)&tl[o] = ll;
    }
}

// ---------------------------------------------------------------------------
// Single bf16x3 GEMM, C = A @ B^T, bf16 hi/lo out. 128x128 tile, BK=64:
// 96 MFMA per wave per barrier-pair, 64 KB LDS, 2 blocks/CU.
// (round-1 verified structure, 0 bank conflicts) + T1 XCD tile remap.
// ---------------------------------------------------------------------------
__global__ __launch_bounds__(256, 2) void gemm3_single(const bf16* __restrict__ Ah,
                                                       const bf16* __restrict__ Al,
                                                       const bf16* __restrict__ Bh,
                                                       const bf16* __restrict__ Bl,
                                                       bf16* __restrict__ C0,
                                                       bf16* __restrict__ C1,
                                                       int M, int N, int K) {
    __shared__ bf16 sAh[128 * 64], sAl[128 * 64];
    __shared__ bf16 sBh[128 * 64], sBl[128 * 64];

    const int tid  = threadIdx.x;
    const int wave = tid >> 6;
    const int lane = tid & 63;
    int n0, m0;
    xcd_tile(n0, m0);
    const int wm   = wave & 1;
    const int wn   = wave >> 1;

    floatx4 acc[4][4];
#pragma unroll
    for (int i = 0; i < 4; ++i)
#pragma unroll
        for (int j = 0; j < 4; ++j) acc[i][j] = (floatx4){0.f, 0.f, 0.f, 0.f};

    const int lr  = lane & 15;
    const int cc8 = (lane >> 4) << 3;
    const int sw  = lr & 7;           // == row & 7 for all fragment rows

    for (int kt = 0; kt < K; kt += 64) {
        // each tile: 128 rows x 64 cols = 1024 16B-chunks -> 4 passes x 256 thr
#pragma unroll
        for (int i = 0; i < 4; ++i) {
            const int q = ((i * 4 + wave) << 6) + lane;   // 0..1023 (LDS slot)
            const int r = q >> 3;                         // row 0..127
            const int c = (q & 7) ^ (r & 7);              // swizzled src chunk
            const int e = q << 3;                         // linear LDS dest
            const size_t ga = (size_t)(m0 + r) * K + kt + c * 8;
            const size_t gb = (size_t)(n0 + r) * K + kt + c * 8;
            load_lds16(&Ah[ga], &sAh[e]);
            load_lds16(&Al[ga], &sAl[e]);
            load_lds16(&Bh[gb], &sBh[e]);
            load_lds16(&Bl[gb], &sBl[e]);
        }
        __syncthreads();

#pragma unroll
        for (int ks = 0; ks < 2; ++ks) {
            const int cb = (ks << 2) + (cc8 >> 3);        // logical chunk 0..7
            const int co = (cb ^ sw) << 3;                // swizzled elem off
            bf16x8 ah[4], al[4], bh[4], bl[4];
#pragma unroll
            for (int mi = 0; mi < 4; ++mi) {
                const int off = ((wm * 64 + mi * 16 + lr) << 6) + co;
                ah[mi] = *(const bf16x8*)&sAh[off];
                al[mi] = *(const bf16x8*)&sAl[off];
            }
#pragma unroll
            for (int ni = 0; ni < 4; ++ni) {
                const int off = ((wn * 64 + ni * 16 + lr) << 6) + co;
                bh[ni] = *(const bf16x8*)&sBh[off];
                bl[ni] = *(const bf16x8*)&sBl[off];
            }

#pragma unroll
            for (int mi = 0; mi < 4; ++mi)
#pragma unroll
                for (int ni = 0; ni < 4; ++ni) {
                    acc[mi][ni] = __builtin_amdgcn_mfma_f32_16x16x32_bf16(
                        ah[mi], bh[ni], acc[mi][ni], 0, 0, 0);
                    acc[mi][ni] = __builtin_amdgcn_mfma_f32_16x16x32_bf16(
                        al[mi], bh[ni], acc[mi][ni], 0, 0, 0);
                    acc[mi][ni] = __builtin_amdgcn_mfma_f32_16x16x32_bf16(
                        ah[mi], bl[ni], acc[mi][ni], 0, 0, 0);
                }
        }
        __syncthreads();
    }

    const int rq = (lane >> 4) << 2;
    const int cl = lane & 15;
#pragma unroll
    for (int mi = 0; mi < 4; ++mi) {
#pragma unroll
        for (int ni = 0; ni < 4; ++ni) {
            const int col = n0 + wn * 64 + ni * 16 + cl;
#pragma unroll
            for (int r = 0; r < 4; ++r) {
                const int row = m0 + wm * 64 + mi * 16 + rq + r;
                const size_t idx = (size_t)row * N + col;
                const HL u = split2(acc[mi][ni][r]);
                C0[idx] = u.h;
                C1[idx] = u.l;
            }
        }
    }
}

// ---------------------------------------------------------------------------
// Dual GEMM (bf16x3): male = xo @ Wcm^T, female = xo @ Wcf^T in ONE kernel —
// A-tiles staged once for both products. 6 LDS tiles (48 KB), fp32 out.
// (round-1 verified structure, 0 bank conflicts) + T1 XCD tile remap.
// ---------------------------------------------------------------------------
__global__ __launch_bounds__(256, 2) void gemm3_dual(const bf16* __restrict__ Ah,
                                                     const bf16* __restrict__ Al,
                                                     const bf16* __restrict__ Bmh,
                                                     const bf16* __restrict__ Bml,
                                                     const bf16* __restrict__ Bfh,
                                                     const bf16* __restrict__ Bfl,
                                                     float* __restrict__ Cm,
                                                     float* __restrict__ Cf,
                                                     int M, int N, int K) {
    __shared__ bf16 sAh[4096], sAl[4096];
    __shared__ bf16 sMh[4096], sMl[4096];
    __shared__ bf16 sFh[4096], sFl[4096];

    const int tid  = threadIdx.x;
    const int wave = tid >> 6;
    const int lane = tid & 63;
    int n0, m0;
    xcd_tile(n0, m0);
    const int wm   = wave & 1;
    const int wn   = wave >> 1;

    floatx4 am[4][4], af[4][4];
#pragma unroll
    for (int i = 0; i < 4; ++i)
#pragma unroll
        for (int j = 0; j < 4; ++j) {
            am[i][j] = (floatx4){0.f, 0.f, 0.f, 0.f};
            af[i][j] = (floatx4){0.f, 0.f, 0.f, 0.f};
        }

    const int lr  = lane & 15;
    const int cc8 = (lane >> 4) << 3;
    const int cq  = cc8 >> 3;         // logical chunk 0..3
    const int hsw = lr >> 1;          // == (row>>1)&7 for all fragment rows

    for (int kt = 0; kt < K; kt += 32) {
#pragma unroll
        for (int i = 0; i < 2; ++i) {
            const int q = ((i * 4 + wave) << 6) + lane;   // 0..511 (LDS slot)
            const int p = q ^ ((q >> 3) & 7);             // swizzled src chunk-id
            const int r = p >> 2, c = p & 3;
            const int e = q << 3;                         // linear LDS dest
            const size_t ga = (size_t)(m0 + r) * K + kt + c * 8;
            const size_t gb = (size_t)(n0 + r) * K + kt + c * 8;
            load_lds16(&Ah[ga],  &sAh[e]);
            load_lds16(&Al[ga],  &sAl[e]);
            load_lds16(&Bmh[gb], &sMh[e]);
            load_lds16(&Bml[gb], &sMl[e]);
            load_lds16(&Bfh[gb], &sFh[e]);
            load_lds16(&Bfl[gb], &sFl[e]);
        }
        __syncthreads();

        bf16x8 ah[4], al[4];
#pragma unroll
        for (int mi = 0; mi < 4; ++mi) {
            const int ql  = ((wm * 64 + mi * 16 + lr) << 2) + cq;
            const int off = (ql ^ hsw) << 3;
            ah[mi] = *(const bf16x8*)&sAh[off];
            al[mi] = *(const bf16x8*)&sAl[off];
        }
#pragma unroll
        for (int ni = 0; ni < 4; ++ni) {
            const int ql  = ((wn * 64 + ni * 16 + lr) << 2) + cq;
            const int off = (ql ^ hsw) << 3;
            const bf16x8 mh = *(const bf16x8*)&sMh[off];
            const bf16x8 ml = *(const bf16x8*)&sMl[off];
            const bf16x8 fh = *(const bf16x8*)&sFh[off];
            const bf16x8 fl = *(const bf16x8*)&sFl[off];
#pragma unroll
            for (int mi = 0; mi < 4; ++mi) {
                am[mi][ni] = __builtin_amdgcn_mfma_f32_16x16x32_bf16(
                    ah[mi], mh, am[mi][ni], 0, 0, 0);
                am[mi][ni] = __builtin_amdgcn_mfma_f32_16x16x32_bf16(
                    al[mi], mh, am[mi][ni], 0, 0, 0);
                am[mi][ni] = __builtin_amdgcn_mfma_f32_16x16x32_bf16(
                    ah[mi], ml, am[mi][ni], 0, 0, 0);
                af[mi][ni] = __builtin_amdgcn_mfma_f32_16x16x32_bf16(
                    ah[mi], fh, af[mi][ni], 0, 0, 0);
                af[mi][ni] = __builtin_amdgcn_mfma_f32_16x16x32_bf16(
                    al[mi], fh, af[mi][ni], 0, 0, 0);
                af[mi][ni] = __builtin_amdgcn_mfma_f32_16x16x32_bf16(
                    ah[mi], fl, af[mi][ni], 0, 0, 0);
            }
        }
        __syncthreads();
    }

    const int rq = (lane >> 4) << 2;
    const int cl = lane & 15;
#pragma unroll
    for (int mi = 0; mi < 4; ++mi) {
#pragma unroll
        for (int ni = 0; ni < 4; ++ni) {
            const int col = n0 + wn * 64 + ni * 16 + cl;
#pragma unroll
            for (int r = 0; r < 4; ++r) {
                const int row = m0 + wm * 64 + mi * 16 + rq + r;
                const size_t idx = (size_t)row * N + col;
                Cm[idx] = am[mi][ni][r];
                Cf[idx] = af[mi][ni][r];
            }
        }
    }
}

// ---------------------------------------------------------------------------
// Combine: phase_lock = sigmoid(male . female); out = pl*male + (1-pl)*female
// ---------------------------------------------------------------------------
__global__ __launch_bounds__(256) void combine_kernel(const float* __restrict__ male,
                                                      const float* __restrict__ female,
                                                      float* __restrict__ out) {
    const int b = blockIdx.x;
    const int t = threadIdx.x;

    const floatx4* m4 = (const floatx4*)(male   + (size_t)b * D_OUT);
    const floatx4* f4 = (const floatx4*)(female + (size_t)b * D_OUT);
    const floatx4 mv0 = m4[t * 2], mv1 = m4[t * 2 + 1];
    const floatx4 fv0 = f4[t * 2], fv1 = f4[t * 2 + 1];

    float s = 0.f;
#pragma unroll
    for (int j = 0; j < 4; ++j) s += mv0[j] * fv0[j] + mv1[j] * fv1[j];
#pragma unroll
    for (int off = 32; off > 0; off >>= 1) s += __shfl_down(s, off, 64);

    __shared__ float red[4];
    const int wave = t >> 6, lane = t & 63;
    if (lane == 0) red[wave] = s;
    __syncthreads();
    const float dot = red[0] + red[1] + red[2] + red[3];
    const float pl  = 1.f / (1.f + expf(-dot));

    floatx4 o0, o1;
#pragma unroll
    for (int j = 0; j < 4; ++j) {
        o0[j] = pl * mv0[j] + (1.f - pl) * fv0[j];
        o1[j] = pl * mv1[j] + (1.f - pl) * fv1[j];
    }
    floatx4* o4 = (floatx4*)(out + (size_t)b * D_OUT);
    o4[t * 2]     = o0;
    o4[t * 2 + 1] = o1;
}

// ---------------------------------------------------------------------------
// Pipeline:  male = xo @ (Wm P Wfl)^T,  female = xo @ (Wfe_flip P Wfl)^T
// ---------------------------------------------------------------------------
extern "C" void kernel_launch(void* const* d_in, const int* in_sizes, int n_in,
                              void* d_out, int out_size, void* d_ws, size_t ws_size,
                              hipStream_t stream) {
    const float* x   = (const float*)d_in[0];
    const float* Wfl = (const float*)d_in[1]; // [7,512,2048] == [3584,2048]
    const float* Wm  = (const float*)d_in[2]; // [2048,3584]
    const float* Wfe = (const float*)d_in[3]; // [2048,3584]
    float* out = (float*)d_out;
    (void)in_sizes; (void)n_in; (void)out_size; (void)ws_size;

    char* ws = (char*)d_ws;
    bf16*  xo_hi   = (bf16*)(ws);                    // 4096x2048 = 16,777,216
    bf16*  xo_lo   = (bf16*)(ws + 16777216);         // 16,777,216
    bf16*  Wc_hi   = (bf16*)(ws + 33554432);         // 4096x2048 = 16,777,216
    bf16*  Wc_lo   = (bf16*)(ws + 50331648);         // 16,777,216 -> 67,108,864
    // overlay phase A (dead after gemm3_single):
    bf16*  WflT_hi = (bf16*)(ws + 67108864);         // 2048x3584 = 14,680,064
    bf16*  WflT_lo = (bf16*)(ws + 81788928);         // -> 96,468,992
    bf16*  Wcat_hi = (bf16*)(ws + 96468992);         // 4096x3584 = 29,360,128
    bf16*  Wcat_lo = (bf16*)(ws + 125829120);        // -> 155,189,248
    // overlay phase B (after gemm3_single):
    float* male    = (float*)(ws + 67108864);        // 4096x2048 f32 = 33,554,432
    float* female  = (float*)(ws + 100663296);       // -> 134,217,728

    // 1. vesica scaling (fp32 -> bf16 hi/lo)
    vesica_kernel<<<B_DIM, 256, 0, stream>>>(x, xo_hi, xo_lo);

    // 2. transpose + phase-scale + split Wfl -> WflT [2048, 3584]
    tsplit_kernel<<<dim3(D_IN / 64, D_HID / 64), 256, 0, stream>>>(Wfl, WflT_hi, WflT_lo);

    // 3. Wcat = [Wm ; Wfe_flip], bf16 hi/lo [4096, 3584] (fused, one launch)
    wcat_kernel<<<(2 * D_OUT * (D_HID / 8)) / 256, 256, 0, stream>>>(
        Wm, Wfe, Wcat_hi, Wcat_lo);

    // 4. weight combine: Wc[4096,2048] = Wcat @ WflT^T  (K=3584, BK=64)
    gemm3_single<<<dim3(D_IN / 128, (2 * D_OUT) / 128), 256, 0, stream>>>(
        Wcat_hi, Wcat_lo, WflT_hi, WflT_lo, Wc_hi, Wc_lo,
        2 * D_OUT, D_IN, D_HID);

    // 5. main dual GEMM: male/female = xo @ Wc^T  (K=2048, fp32 out)
    gemm3_dual<<<dim3(D_OUT / 128, B_DIM / 128), 256, 0, stream>>>(
        xo_hi, xo_lo,
        Wc_hi, Wc_lo,
        Wc_hi + (size_t)D_OUT * D_IN, Wc_lo + (size_t)D_OUT * D_IN,
        male, female, B_DIM, D_OUT, D_IN);

    // 6. sigmoid phase-lock blend (fp32 out)
    combine_kernel<<<B_DIM, 256, 0, stream>>>(male, female, out);
}